// Round 14
// baseline (164.763 us; speedup 1.0000x reference)
//
#include <hip/hip_runtime.h>
#include <math.h>

// Problem constants (B,C,H,W = 32,512,56,56; top_t = round(3136*0.1) = 314)
#define NB 32
#define NC 512
#define NH 56
#define NW 56
#define NHW 3136
#define TOPT 314
#define NR 32
#define RBUCK 2048

typedef float f32x4 __attribute__((ext_vector_type(4)));

__device__ __forceinline__ unsigned int f2s(float f) {
    unsigned int b = __float_as_uint(f);
    return (b & 0x80000000u) ? ~b : (b | 0x80000000u);
}
__device__ __forceinline__ float s2f(unsigned int u) {
    unsigned int b = (u & 0x80000000u) ? (u ^ 0x80000000u) : ~u;
    return __uint_as_float(b);
}

// Packed suffix scan + per-row crossing search. Reads vv[8], g; updates
// prefA/kA/prefB/kB via shared sh_pref/sh_k. 2 barriers.
#define SCAN_CROSS(SHIFT, STORE_CNT)                                          \
    {                                                                         \
        unsigned int S = g;                                                   \
        _Pragma("unroll")                                                     \
        for (int off = 1; off < 64; off <<= 1) {                              \
            unsigned int t2 = __shfl_down(S, off);                            \
            if (lane + off < 64) S += t2;                                     \
        }                                                                     \
        if (lane == 0) wtot[wid] = S;                                         \
        __syncthreads();                                                      \
        unsigned int hi = 0u;                                                 \
        if (wid < 3) hi += wtot[wid + 1];                                     \
        if (wid < 2) hi += wtot[wid + 2];                                     \
        if (wid < 1) hi += wtot[wid + 3];                                     \
        S += hi;                                                              \
        const unsigned int SloT = S & 0xFFFFu, ShiT = S >> 16;                \
        const unsigned int gLo = g & 0xFFFFu, gHi = g >> 16;                  \
        const unsigned int aboveLo = SloT - gLo, aboveHi = ShiT - gHi;        \
        if (SloT >= kA && aboveLo < kA) {                                     \
            unsigned int cum = aboveLo;                                       \
            _Pragma("unroll")                                                 \
            for (int bb = 7; bb >= 0; --bb) {                                 \
                const unsigned int hh = vv[bb] & 0xFFFFu;                     \
                if (cum + hh >= kA) {                                         \
                    sh_pref[0] = prefA | ((unsigned int)(8 * tid + bb) << (SHIFT)); \
                    sh_k[0] = kA - cum;                                       \
                    if (STORE_CNT) sh_cnt[0] = hh;                            \
                    break;                                                    \
                }                                                             \
                cum += hh;                                                    \
            }                                                                 \
        }                                                                     \
        if (ShiT >= kB && aboveHi < kB) {                                     \
            unsigned int cum = aboveHi;                                       \
            _Pragma("unroll")                                                 \
            for (int bb = 7; bb >= 0; --bb) {                                 \
                const unsigned int hh = vv[bb] >> 16;                         \
                if (cum + hh >= kB) {                                         \
                    sh_pref[1] = prefB | ((unsigned int)(8 * tid + bb) << (SHIFT)); \
                    sh_k[1] = kB - cum;                                       \
                    if (STORE_CNT) sh_cnt[1] = hh;                            \
                    break;                                                    \
                }                                                             \
                cum += hh;                                                    \
            }                                                                 \
        }                                                                     \
        __syncthreads();                                                      \
        prefA = sh_pref[0]; kA = sh_k[0];                                     \
        prefB = sh_pref[1]; kB = sh_k[1];                                     \
    }

// ---------------- Kernel 1: exact top-314 sum + max, TWO rows/block ------
// R13 skeleton (round-2 skip certificate, lane-parity round-0 split,
// SWAR-packed 2 rows/block) + phase diet:
//  - zero-after-fold: each thread zeroes the exact words it folded, inside
//    the fold phase (same-thread RAW only; 2 barriers before next atomics)
//    -> the separate per-round zero+barrier prologue is deleted.
//  - round-1 zeroing moved into the rare (!skip2) round-2 prologue.
//  - fold via uint4 LDS reads (4x fewer DS instructions, same banks).
// Common-path barriers 9 -> 8; zero work for round 2 off the common path.
__global__ __launch_bounds__(256) void topk_pool_kernel(
        const float* __restrict__ x,
        float* __restrict__ pool_avg, float* __restrict__ pool_max) {
    __shared__ unsigned int hist[2][RBUCK];      // 16 KB
    __shared__ unsigned int wtot[4];
    __shared__ unsigned int sh_pref[2], sh_k[2], sh_cnt[2];
    __shared__ float redsA[4], redsB[4];
    __shared__ unsigned int redmA[4], redmB[4];

    const int rowA = blockIdx.x * 2;
    const int tid = threadIdx.x;
    const int wid = tid >> 6;
    const int lane = tid & 63;
    const float* xa = x + (size_t)rowA * NHW;
    const float* xb = xa + NHW;
    const float4* xa4 = (const float4*)xa;
    const float4* xb4 = (const float4*)xb;

    // 3136 = 12*256 + 64: three float4 loads + one scalar (tid<64), per row
    float4 a0 = xa4[tid], a1 = xa4[256 + tid], a2 = xa4[512 + tid];
    float4 b0 = xb4[tid], b1 = xb4[256 + tid], b2 = xb4[512 + tid];
    const bool has13 = (tid < 64);
    float exA = has13 ? xa[3072 + tid] : 0.f;
    float exB = has13 ? xb[3072 + tid] : 0.f;

    unsigned int u[13], w[13];
    u[0] = f2s(a0.x); u[1] = f2s(a0.y); u[2]  = f2s(a0.z); u[3]  = f2s(a0.w);
    u[4] = f2s(a1.x); u[5] = f2s(a1.y); u[6]  = f2s(a1.z); u[7]  = f2s(a1.w);
    u[8] = f2s(a2.x); u[9] = f2s(a2.y); u[10] = f2s(a2.z); u[11] = f2s(a2.w);
    u[12] = f2s(exA);
    w[0] = f2s(b0.x); w[1] = f2s(b0.y); w[2]  = f2s(b0.z); w[3]  = f2s(b0.w);
    w[4] = f2s(b1.x); w[5] = f2s(b1.y); w[6]  = f2s(b1.z); w[7]  = f2s(b1.w);
    w[8] = f2s(b2.x); w[9] = f2s(b2.y); w[10] = f2s(b2.z); w[11] = f2s(b2.w);
    w[12] = f2s(exB);

    #pragma unroll
    for (int j = 0; j < 12; ++j) {
        asm volatile("" : "+v"(u[j]));
        asm volatile("" : "+v"(w[j]));
    }

    unsigned int prefA = 0u, prefB = 0u;
    unsigned int kA = TOPT, kB = TOPT;
    const uint4 z4 = make_uint4(0u, 0u, 0u, 0u);

    // ===== initial zero (both banks) =====
    {
        uint4* h0 = (uint4*)hist[0];
        uint4* h1 = (uint4*)hist[1];
        h0[tid] = z4; h0[256 + tid] = z4;
        h1[tid] = z4; h1[256 + tid] = z4;
    }
    __syncthreads();

    // ===== round 0: bits [31:21], lane-parity split across two banks =====
    {
        unsigned int* h = hist[lane & 1];
        #pragma unroll
        for (int j = 0; j < 13; ++j) {
            const bool live = (j < 12) || has13;
            if (live) atomicAdd(&h[u[j] >> 21], 1u);
            if (live) atomicAdd(&h[w[j] >> 21], 65536u);
        }
    }
    __syncthreads();
    unsigned int vv[8];
    unsigned int g;
    {   // fold both banks (uint4) + zero own words for the next round
        uint4* h0 = (uint4*)hist[0];
        uint4* h1 = (uint4*)hist[1];
        uint4 p0 = h0[2 * tid], p1 = h0[2 * tid + 1];
        uint4 q0 = h1[2 * tid], q1 = h1[2 * tid + 1];
        vv[0] = p0.x + q0.x; vv[1] = p0.y + q0.y;
        vv[2] = p0.z + q0.z; vv[3] = p0.w + q0.w;
        vv[4] = p1.x + q1.x; vv[5] = p1.y + q1.y;
        vv[6] = p1.z + q1.z; vv[7] = p1.w + q1.w;
        g = vv[0] + vv[1] + vv[2] + vv[3] + vv[4] + vv[5] + vv[6] + vv[7];
        h0[2 * tid] = z4; h0[2 * tid + 1] = z4;   // zero what we read; two
        h1[2 * tid] = z4; h1[2 * tid + 1] = z4;   // barriers before reuse
    }
    SCAN_CROSS(21, 0)

    // ===== round 1: bits [20:10], single bank =====
    #pragma unroll
    for (int j = 0; j < 13; ++j) {
        const bool live = (j < 12) || has13;
        if (live && ((u[j] & 0xFFE00000u) == prefA))
            atomicAdd(&hist[0][(u[j] >> 10) & (RBUCK - 1u)], 1u);
        if (live && ((w[j] & 0xFFE00000u) == prefB))
            atomicAdd(&hist[0][(w[j] >> 10) & (RBUCK - 1u)], 65536u);
    }
    __syncthreads();
    {   // fold single bank; NO zero (round 2 is rare, zeroes for itself)
        uint4* h0 = (uint4*)hist[0];
        uint4 p0 = h0[2 * tid], p1 = h0[2 * tid + 1];
        vv[0] = p0.x; vv[1] = p0.y; vv[2] = p0.z; vv[3] = p0.w;
        vv[4] = p1.x; vv[5] = p1.y; vv[6] = p1.z; vv[7] = p1.w;
        g = vv[0] + vv[1] + vv[2] + vv[3] + vv[4] + vv[5] + vv[6] + vv[7];
    }
    SCAN_CROSS(10, 1)
    const bool skip2 = (kA == sh_cnt[0]) && (kB == sh_cnt[1]);

    // ===== round 2: bits [10:0] — only when ties are unresolved (~6%) ====
    if (!skip2) {
        {   // zero hist[0] (was left dirty by round 1)
            uint4* h0 = (uint4*)hist[0];
            h0[tid] = z4; h0[256 + tid] = z4;
        }
        __syncthreads();
        #pragma unroll
        for (int j = 0; j < 13; ++j) {
            const bool live = (j < 12) || has13;
            if (live && ((u[j] & 0xFFFFFC00u) == prefA))
                atomicAdd(&hist[0][u[j] & (RBUCK - 1u)], 1u);
            if (live && ((w[j] & 0xFFFFFC00u) == prefB))
                atomicAdd(&hist[0][w[j] & (RBUCK - 1u)], 65536u);
        }
        __syncthreads();
        {
            uint4* h0 = (uint4*)hist[0];
            uint4 p0 = h0[2 * tid], p1 = h0[2 * tid + 1];
            vv[0] = p0.x; vv[1] = p0.y; vv[2] = p0.z; vv[3] = p0.w;
            vv[4] = p1.x; vv[5] = p1.y; vv[6] = p1.z; vv[7] = p1.w;
            g = vv[0] + vv[1] + vv[2] + vv[3] + vv[4] + vv[5] + vv[6] + vv[7];
        }
        SCAN_CROSS(0, 0)
    }

    // ---- final: per-row sum of top-314 (+ ties), and row max ----
    const unsigned int tA = prefA, tB = prefB;
    float sumA = 0.f, sumB = 0.f;
    unsigned int mA = 0u, mB = 0u;
    if (skip2) {
        // top-314 set is exactly {u >= pref22}; no tie correction needed
        #pragma unroll
        for (int j = 0; j < 13; ++j) {
            const bool live = (j < 12) || has13;
            if (live) {
                mA = max(mA, u[j]);
                if (u[j] >= tA) sumA += s2f(u[j]);
                mB = max(mB, w[j]);
                if (w[j] >= tB) sumB += s2f(w[j]);
            }
        }
    } else {
        #pragma unroll
        for (int j = 0; j < 13; ++j) {
            const bool live = (j < 12) || has13;
            if (live) {
                mA = max(mA, u[j]);
                if (u[j] > tA) sumA += s2f(u[j]);
                mB = max(mB, w[j]);
                if (w[j] > tB) sumB += s2f(w[j]);
            }
        }
    }
    #pragma unroll
    for (int off = 32; off > 0; off >>= 1) {
        sumA += __shfl_down(sumA, off);
        sumB += __shfl_down(sumB, off);
        mA = max(mA, __shfl_down(mA, off));
        mB = max(mB, __shfl_down(mB, off));
    }
    if (lane == 0) { redsA[wid] = sumA; redsB[wid] = sumB;
                     redmA[wid] = mA;   redmB[wid] = mB; }
    __syncthreads();
    if (tid == 0) {
        const float tieA = skip2 ? 0.f : (float)kA * s2f(tA);
        const float tieB = skip2 ? 0.f : (float)kB * s2f(tB);
        float totA = redsA[0] + redsA[1] + redsA[2] + redsA[3] + tieA;
        float totB = redsB[0] + redsB[1] + redsB[2] + redsB[3] + tieB;
        pool_avg[rowA]     = totA * (1.0f / (float)TOPT);
        pool_avg[rowA + 1] = totB * (1.0f / (float)TOPT);
        pool_max[rowA]     = s2f(max(max(redmA[0], redmA[1]), max(redmA[2], redmA[3])));
        pool_max[rowA + 1] = s2f(max(max(redmB[0], redmB[1]), max(redmB[2], redmB[3])));
    }
}

// ---------------- Kernel 2: channel-MLP + sigmoid -> s[b,c] --------------
// Layer 1 uses all 256 threads: 32 units x 2 pools x 4 K-segments of 128,
// partials combined via LDS (isolated win in R10: -4.4us vs 64-thread).
__global__ __launch_bounds__(256) void mlp_kernel(
        const float* __restrict__ pool_avg, const float* __restrict__ pool_max,
        const float* __restrict__ w1, const float* __restrict__ b1,
        const float* __restrict__ w2, const float* __restrict__ b2,
        float* __restrict__ s_out) {
    __shared__ float pa[NC], pm[NC], part[64][4], h1a[NR], h1m[NR];
    const int b = blockIdx.x, tid = threadIdx.x;
    for (int c = tid; c < NC; c += 256) {
        pa[c] = pool_avg[b * NC + c];
        pm[c] = pool_max[b * NC + c];
    }
    __syncthreads();
    {
        const int r = tid & 31;              // hidden unit
        const int half = (tid >> 5) & 1;     // 0=avg, 1=max
        const int seg = tid >> 6;            // K-segment 0..3
        const float* p = (half ? pm : pa) + seg * 128;
        const float* wrow = w1 + r * NC + seg * 128;
        float acc = 0.f;
        #pragma unroll 4
        for (int c = 0; c < 128; ++c) acc = fmaf(p[c], wrow[c], acc);
        part[tid & 63][seg] = acc;
    }
    __syncthreads();
    if (tid < 64) {
        const int r = tid & 31;
        float acc = b1[r] + part[tid][0] + part[tid][1]
                  + part[tid][2] + part[tid][3];
        float h = fmaxf(acc, 0.f);
        if (tid < 32) h1a[r] = h; else h1m[r] = h;
    }
    __syncthreads();
    for (int c = tid; c < NC; c += 256) {
        float acc = 2.f * b2[c];
        const float* wrow = w2 + c * NR;
        for (int r = 0; r < NR; ++r) acc += (h1a[r] + h1m[r]) * wrow[r];
        s_out[b * NC + c] = 1.f / (1.f + expf(-acc));
    }
}

// ---------------- Kernel 3: channel max/mean of x*s -> cp ----------------
__global__ __launch_bounds__(256) void spatial_pool_kernel(
        const float* __restrict__ x, const float* __restrict__ s,
        float* __restrict__ cp_max, float* __restrict__ cp_avg) {
    __shared__ float sc[NC];
    __shared__ float4 pmx[7][32];
    __shared__ float4 psm[7][32];
    const int b = blockIdx.y, tid = threadIdx.x;
    const int qo = tid & 31;                 // float4-pixel within tile
    const int cg = tid >> 5;                 // channel group 0..7
    const int q = blockIdx.x * 32 + qo;      // float4 index, 0..783 valid
    for (int c = tid; c < NC; c += 256) sc[c] = s[b * NC + c];
    __syncthreads();
    const float4* xb4 = (const float4*)(x + (size_t)b * NC * NHW);
    float4 mx = make_float4(-INFINITY, -INFINITY, -INFINITY, -INFINITY);
    float4 sm = make_float4(0.f, 0.f, 0.f, 0.f);
    const bool valid = (q < NHW / 4);
    if (valid) {
        #pragma unroll 2
        for (int c = cg * 64; c < cg * 64 + 64; ++c) {
            float4 v = xb4[(size_t)c * (NHW / 4) + q];
            const float scv = sc[c];
            v.x *= scv; v.y *= scv; v.z *= scv; v.w *= scv;
            mx.x = fmaxf(mx.x, v.x); mx.y = fmaxf(mx.y, v.y);
            mx.z = fmaxf(mx.z, v.z); mx.w = fmaxf(mx.w, v.w);
            sm.x += v.x; sm.y += v.y; sm.z += v.z; sm.w += v.w;
        }
    }
    if (cg > 0 && valid) { pmx[cg - 1][qo] = mx; psm[cg - 1][qo] = sm; }
    __syncthreads();
    if (cg == 0 && valid) {
        #pragma unroll
        for (int i = 0; i < 7; ++i) {
            const float4 m2 = pmx[i][qo];
            const float4 s2 = psm[i][qo];
            mx.x = fmaxf(mx.x, m2.x); mx.y = fmaxf(mx.y, m2.y);
            mx.z = fmaxf(mx.z, m2.z); mx.w = fmaxf(mx.w, m2.w);
            sm.x += s2.x; sm.y += s2.y; sm.z += s2.z; sm.w += s2.w;
        }
        const float inv = 1.0f / (float)NC;
        sm.x *= inv; sm.y *= inv; sm.z *= inv; sm.w *= inv;
        ((float4*)(cp_max + b * NHW))[q] = mx;
        ((float4*)(cp_avg + b * NHW))[q] = sm;
    }
}

// ---------------- Kernel 4: 7x7 conv + BN + sigmoid -> g[b,hw] -----------
__global__ __launch_bounds__(256) void conv_gate_kernel(
        const float* __restrict__ cp_max, const float* __restrict__ cp_avg,
        const float* __restrict__ conv_w,
        const float* __restrict__ gamma, const float* __restrict__ beta,
        const float* __restrict__ mean, const float* __restrict__ var,
        float* __restrict__ g) {
    __shared__ float wgt[98];
    const int b = blockIdx.y, tid = threadIdx.x;
    const int p = blockIdx.x * 256 + tid;
    if (tid < 98) wgt[tid] = conv_w[tid];
    __syncthreads();
    if (p >= NHW) return;
    const int h = p / NW, w = p - h * NW;
    const float* cm = cp_max + b * NHW;
    const float* ca = cp_avg + b * NHW;
    float acc = 0.f;
    for (int i = 0; i < 7; ++i) {
        const int hh = h - 3 + i;
        if (hh < 0 || hh >= NH) continue;
        for (int j = 0; j < 7; ++j) {
            const int ww = w - 3 + j;
            if (ww < 0 || ww >= NW) continue;
            const int q = hh * NW + ww;
            acc += cm[q] * wgt[i * 7 + j] + ca[q] * wgt[49 + i * 7 + j];
        }
    }
    const float bnv = (acc - mean[0]) * rsqrtf(var[0] + 1e-5f) * gamma[0] + beta[0];
    g[b * NHW + p] = 1.f / (1.f + expf(-bnv));
}

// ---------------- Kernel 5: out = x * s[b,c] * g[b,hw] -------------------
// One block per (b,c) row: scalar s broadcast, nontemporal stores so the
// 205 MB output stream doesn't evict x from L3.
__global__ __launch_bounds__(256) void scale_out_kernel(
        const float* __restrict__ x, const float* __restrict__ s,
        const float* __restrict__ g, float* __restrict__ out) {
    const int bc = blockIdx.x;               // 0..16383
    const int b = bc >> 9;
    const int tid = threadIdx.x;
    const float sv = s[bc];
    const f32x4* xr = (const f32x4*)(x + (size_t)bc * NHW);
    const f32x4* gr = (const f32x4*)(g + (size_t)b * NHW);
    f32x4* orow = (f32x4*)(out + (size_t)bc * NHW);
    #pragma unroll
    for (int i = 0; i < 3; ++i) {            // 3*256 = 768 of 784 float4s
        const int q = tid + 256 * i;
        f32x4 xv = xr[q];
        f32x4 gv = gr[q];
        f32x4 ov = xv * sv * gv;
        __builtin_nontemporal_store(ov, &orow[q]);
    }
    if (tid < 16) {                          // tail: 768..783
        const int q = 768 + tid;
        f32x4 xv = xr[q];
        f32x4 gv = gr[q];
        f32x4 ov = xv * sv * gv;
        __builtin_nontemporal_store(ov, &orow[q]);
    }
}

extern "C" void kernel_launch(void* const* d_in, const int* in_sizes, int n_in,
                              void* d_out, int out_size, void* d_ws, size_t ws_size,
                              hipStream_t stream) {
    const float* x      = (const float*)d_in[0];
    const float* w1     = (const float*)d_in[1];
    const float* b1     = (const float*)d_in[2];
    const float* w2     = (const float*)d_in[3];
    const float* b2     = (const float*)d_in[4];
    const float* conv_w = (const float*)d_in[5];
    const float* gamma  = (const float*)d_in[6];
    const float* beta   = (const float*)d_in[7];
    const float* mean   = (const float*)d_in[8];
    const float* var    = (const float*)d_in[9];
    float* out = (float*)d_out;

    float* ws = (float*)d_ws;
    float* pool_avg = ws;                       // 16384
    float* pool_max = ws + 16384;               // 16384
    float* s        = ws + 32768;               // 16384
    float* cp_max   = ws + 49152;               // 100352
    float* cp_avg   = ws + 149504;              // 100352
    float* g        = ws + 249856;              // 100352  (total 1.37 MB)

    topk_pool_kernel<<<NB * NC / 2, 256, 0, stream>>>(x, pool_avg, pool_max);
    mlp_kernel<<<NB, 256, 0, stream>>>(pool_avg, pool_max, w1, b1, w2, b2, s);
    dim3 grid3((NHW / 4 + 31) / 32, NB);        // (25, 32) = 800 blocks
    spatial_pool_kernel<<<grid3, 256, 0, stream>>>(x, s, cp_max, cp_avg);
    dim3 grid4((NHW + 255) / 256, NB);
    conv_gate_kernel<<<grid4, 256, 0, stream>>>(cp_max, cp_avg, conv_w,
                                                gamma, beta, mean, var, g);
    scale_out_kernel<<<NB * NC, 256, 0, stream>>>(x, s, g, out);
}